// Round 1
// 795.973 us; speedup vs baseline: 1.0987x; 1.0987x over previous
//
#include <hip/hip_runtime.h>

// ---------------------------------------------------------------------------
// out[n] = sum_f ( z_nf^T W_f z_nf - log(clip(det(W_f S1_f + I),1e-5,1e5)) )
//          + log(n1/n2)
// N=4096, K=256, P2=96
//
// R4: det_kernel LU step de-serialized:
//  - row update fully unrolled in 3 uniform-branch groups of 8 float4 chunks
//    (dead L-region chunks updated too -- never read again, provably safe)
//  - pivot argmax via packed u32 key (6 shfl_xor + v_max_u32), signed pivot
//    value recovered by one shuffle -> no Al[k][k] re-read
//  - swap restricted to live chunks
// quad/finalize unchanged (passed, ~110 us).
// ---------------------------------------------------------------------------

typedef __attribute__((ext_vector_type(8))) short bf16x8;
typedef __attribute__((ext_vector_type(4))) float f32x4;

__device__ __forceinline__ unsigned short f2bf(float x) {
  unsigned int u = __builtin_bit_cast(unsigned int, x);
  u += 0x7fffu + ((u >> 16) & 1u);   // round-to-nearest-even
  return (unsigned short)(u >> 16);
}
__device__ __forceinline__ float bf2f(unsigned short h) {
  unsigned int u = ((unsigned int)h) << 16;
  return __builtin_bit_cast(float, u);
}

// ---------------------------------------------------------------------------
// Kernel 1: per-frequency logdet, one wave per frequency.
// ---------------------------------------------------------------------------
#define ALD 100   // Al row stride (dwords); 100 % 32 == 4 -> uniform b128 banks
#define WLD 35    // Wc row stride; 12*35 % 32 == 4 -> GEMM W-reads spread banks

__global__ __launch_bounds__(64) void det_kernel(
    const float* __restrict__ W, const float* __restrict__ S1,
    float* __restrict__ logdet) {
  __shared__ alignas(16) float Al[96 * ALD];   // 38,400 B
  __shared__ alignas(16) float Wc[96 * WLD];   // 13,440 B
  __shared__ alignas(16) float Sc[32 * 100];   // 12,800 B   (total 64,640 B)

  const int lane = threadIdx.x;
  const int f = blockIdx.x;
  const float* Wg = W + (size_t)f * 9216;
  const float* Sg = S1 + (size_t)f * 9216;

  const int i0 = (lane >> 3) * 12;   // lane tile: rows i0..i0+11
  const int j0 = (lane & 7) * 12;    //            cols j0..j0+11

  float acc[12][12];
#pragma unroll
  for (int a = 0; a < 12; ++a)
#pragma unroll
    for (int b = 0; b < 12; ++b) acc[a][b] = 0.f;

  for (int kc = 0; kc < 3; ++kc) {
    // stage Wc[i][kk] = W[i][kc*32+kk]  (768 float4 loads, b32 scatter)
#pragma unroll
    for (int it = 0; it < 12; ++it) {
      int c = lane + it * 64;          // 0..767
      int i = c >> 3;
      int k4 = (c & 7) << 2;
      const float4 v =
          *reinterpret_cast<const float4*>(Wg + i * 96 + kc * 32 + k4);
      Wc[i * WLD + k4 + 0] = v.x;
      Wc[i * WLD + k4 + 1] = v.y;
      Wc[i * WLD + k4 + 2] = v.z;
      Wc[i * WLD + k4 + 3] = v.w;
    }
    // stage Sc[kk][j] = S1[kc*32+kk][j]  (768 float4, b128 stores)
#pragma unroll
    for (int it = 0; it < 12; ++it) {
      int c = lane + it * 64;
      int kk = c / 24;
      int j4 = (c % 24) << 2;
      const float4 v =
          *reinterpret_cast<const float4*>(Sg + (kc * 32 + kk) * 96 + j4);
      *reinterpret_cast<float4*>(&Sc[kk * 100 + j4]) = v;
    }
    __syncthreads();
#pragma unroll 2
    for (int kk = 0; kk < 32; ++kk) {
      float wv[12];
#pragma unroll
      for (int r = 0; r < 12; ++r) wv[r] = Wc[(i0 + r) * WLD + kk];
      float sv[12];
      const float4 s0 = *reinterpret_cast<const float4*>(&Sc[kk * 100 + j0]);
      const float4 s1 =
          *reinterpret_cast<const float4*>(&Sc[kk * 100 + j0 + 4]);
      const float4 s2 =
          *reinterpret_cast<const float4*>(&Sc[kk * 100 + j0 + 8]);
      sv[0] = s0.x; sv[1] = s0.y; sv[2] = s0.z; sv[3] = s0.w;
      sv[4] = s1.x; sv[5] = s1.y; sv[6] = s1.z; sv[7] = s1.w;
      sv[8] = s2.x; sv[9] = s2.y; sv[10] = s2.z; sv[11] = s2.w;
#pragma unroll
      for (int a = 0; a < 12; ++a)
#pragma unroll
        for (int b = 0; b < 12; ++b) acc[a][b] += wv[a] * sv[b];
    }
    __syncthreads();
  }

  // Al = acc + I
#pragma unroll
  for (int a = 0; a < 12; ++a) {
    int i = i0 + a;
#pragma unroll
    for (int c4 = 0; c4 < 3; ++c4) {
      float4 v;
      v.x = acc[a][c4 * 4 + 0] + ((i == j0 + c4 * 4 + 0) ? 1.f : 0.f);
      v.y = acc[a][c4 * 4 + 1] + ((i == j0 + c4 * 4 + 1) ? 1.f : 0.f);
      v.z = acc[a][c4 * 4 + 2] + ((i == j0 + c4 * 4 + 2) ? 1.f : 0.f);
      v.w = acc[a][c4 * 4 + 3] + ((i == j0 + c4 * 4 + 3) ? 1.f : 0.f);
      *reinterpret_cast<float4*>(&Al[i * ALD + j0 + c4 * 4]) = v;
    }
  }
  __syncthreads();

  // ---- LU with partial pivoting, single wave, straight-line steps ----
  int sgn = 0;
  for (int k = 0; k < 96; ++k) {
    // --- pivot search over col k, rows k..95 (packed-key butterfly) ---
    const int i0r = k + lane;
    const int i1r = k + 64 + lane;
    const float c0 = (i0r < 96) ? Al[i0r * ALD + k] : 0.f;
    const float c1 = (i1r < 96) ? Al[i1r * ALD + k] : 0.f;
    const float a0 = fabsf(c0), a1 = fabsf(c1);
    float bav = a0;
    unsigned bslot = 0u;
    if (a1 > a0) { bav = a1; bslot = 64u; }
    unsigned key = (__float_as_uint(bav) & ~127u) | bslot | (unsigned)lane;
#pragma unroll
    for (int m = 1; m < 64; m <<= 1) {
      unsigned o = (unsigned)__shfl_xor((int)key, m);
      key = key > o ? key : o;
    }
    const int wl = (int)(key & 63u);
    const int slot = (int)((key >> 6) & 1u);
    const float pvv = __shfl(slot ? c1 : c0, wl);  // signed pivot value
    const int bi = k + slot * 64 + wl;

    // --- physical swap rows k <-> bi, live chunks only (bi uniform) ---
    if (bi != k) {
      sgn ^= 1;
      if (lane < 24) {
        const int c = lane;                 // chunk 0..23, cols 4c..4c+3
        if (k <= c * 4 + 3) {               // chunk holds a live column
          float4 x = *reinterpret_cast<float4*>(&Al[k * ALD + c * 4]);
          float4 y = *reinterpret_cast<float4*>(&Al[bi * ALD + c * 4]);
          *reinterpret_cast<float4*>(&Al[k * ALD + c * 4]) = y;
          *reinterpret_cast<float4*>(&Al[bi * ALD + c * 4]) = x;
        }
      }
    }
    __syncthreads();   // single-wave barrier: cheap; orders swap vs update

    // --- row updates: full chunks, unrolled, group-level uniform skip ---
    const float rpv = 1.f / pvv;
    const int rowk = k * ALD;
    const int li0 = k + 1 + lane;
    const bool h0 = li0 < 96;
    float L0 = 0.f;
    if (h0) L0 = Al[li0 * ALD + k] * rpv;
    const int li1 = k + 65 + lane;
    const bool h1 = (k < 31) && (li1 < 96);
    float L1 = 0.f;
    if (h1) L1 = Al[li1 * ALD + k] * rpv;

#pragma unroll
    for (int g = 0; g < 3; ++g) {
      if (k <= 32 * g + 31) {   // group holds live columns (wave-uniform)
        float4 p[8];
#pragma unroll
        for (int c = 0; c < 8; ++c)
          p[c] = *reinterpret_cast<const float4*>(
              &Al[rowk + (g * 8 + c) * 4]);
        if (h0) {
          const int rb = li0 * ALD;
#pragma unroll
          for (int c = 0; c < 8; ++c) {
            float4 a = *reinterpret_cast<float4*>(&Al[rb + (g * 8 + c) * 4]);
            a.x -= L0 * p[c].x;
            a.y -= L0 * p[c].y;
            a.z -= L0 * p[c].z;
            a.w -= L0 * p[c].w;
            *reinterpret_cast<float4*>(&Al[rb + (g * 8 + c) * 4]) = a;
          }
        }
        if (h1) {
          const int rb = li1 * ALD;
#pragma unroll
          for (int c = 0; c < 8; ++c) {
            float4 a = *reinterpret_cast<float4*>(&Al[rb + (g * 8 + c) * 4]);
            a.x -= L1 * p[c].x;
            a.y -= L1 * p[c].y;
            a.z -= L1 * p[c].z;
            a.w -= L1 * p[c].w;
            *reinterpret_cast<float4*>(&Al[rb + (g * 8 + c) * 4]) = a;
          }
        }
      }
    }
    __syncthreads();
  }

  // logdet from U diagonal
  float ls = 0.f;
  int neg = 0;
  for (int kk = lane; kk < 96; kk += 64) {
    float v = Al[kk * ALD + kk];
    ls += logf(fabsf(v));
    if (v < 0.f) neg ^= 1;
  }
#pragma unroll
  for (int m = 1; m < 64; m <<= 1) {
    ls += __shfl_xor(ls, m);
    neg ^= __shfl_xor(neg, m);
  }
  if (lane == 0) {
    const float LMIN = -11.5129254f, LMAX = 11.5129254f;  // log(1e-5), log(1e5)
    float c;
    if (neg ^ sgn) c = LMIN;              // det <= 0 -> clipped to 1e-5
    else c = fminf(fmaxf(ls, LMIN), LMAX);
    logdet[f] = c;
  }
}

// ---------------------------------------------------------------------------
// Kernel 2: quad[n,f] via bf16 MFMA (unchanged — passed, ~110 us).
// ---------------------------------------------------------------------------
#define ZLD 104

__global__ __launch_bounds__(256) void quad_kernel(
    const float* __restrict__ z, const float* __restrict__ W,
    float* __restrict__ partial) {
  __shared__ alignas(16) unsigned short Zb[128 * ZLD];
  __shared__ alignas(16) unsigned short Wb[96 * ZLD];

  const int tid = threadIdx.x;
  const int lane = tid & 63, wave = tid >> 6;
  const int n0 = blockIdx.x * 128;
  const int f0 = blockIdx.y * 16;
  const int lrow = lane & 15;
  const int lq = lane >> 4;
  const int lk8 = lq * 8;
  const int rgrp = tid >> 3;   // 0..31
  const int cgrp = tid & 7;    // 0..7

  float dotacc[2][4];
#pragma unroll
  for (int mt = 0; mt < 2; ++mt)
#pragma unroll
    for (int i = 0; i < 4; ++i) dotacc[mt][i] = 0.f;

  for (int ff = 0; ff < 16; ++ff) {
    const int f = f0 + ff;
    // ---- stage z tile: 8 threads/row, contiguous wave segments ----
#pragma unroll
    for (int p = 0; p < 4; ++p) {
      int r = p * 32 + rgrp;
      const float4* src = reinterpret_cast<const float4*>(
          z + (size_t)(n0 + r) * 24576 + (size_t)f * 96);
#pragma unroll
      for (int cc = 0; cc < 3; ++cc) {
        int c = cgrp + cc * 8;           // 0..23
        float4 d = src[c];
        ushort4 s;
        s.x = f2bf(d.x); s.y = f2bf(d.y); s.z = f2bf(d.z); s.w = f2bf(d.w);
        *reinterpret_cast<ushort4*>(&Zb[r * ZLD + c * 4]) = s;
      }
    }
    // ---- stage W rows (natural layout): 2304 float4, 9 per thread ----
    const float4* wsrc =
        reinterpret_cast<const float4*>(W + (size_t)f * 9216);
#pragma unroll
    for (int it = 0; it < 9; ++it) {
      int c = tid + it * 256;            // 0..2303
      int k = c / 24, q4 = (c % 24) << 2;
      float4 d = wsrc[c];
      ushort4 s;
      s.x = f2bf(d.x); s.y = f2bf(d.y); s.z = f2bf(d.z); s.w = f2bf(d.w);
      *reinterpret_cast<ushort4*>(&Wb[k * ZLD + q4]) = s;
    }
    __syncthreads();

    // ---- MFMA: Y(128x96) = Z @ W^T; wave handles 32 rows ----
    f32x4 acc[2][6];
#pragma unroll
    for (int mt = 0; mt < 2; ++mt)
#pragma unroll
      for (int nt = 0; nt < 6; ++nt) acc[mt][nt] = (f32x4){0.f, 0.f, 0.f, 0.f};

#pragma unroll
    for (int ks = 0; ks < 3; ++ks) {
      bf16x8 a0 = *reinterpret_cast<const bf16x8*>(
          &Zb[(wave * 32 + lrow) * ZLD + ks * 32 + lk8]);
      bf16x8 a1 = *reinterpret_cast<const bf16x8*>(
          &Zb[(wave * 32 + 16 + lrow) * ZLD + ks * 32 + lk8]);
#pragma unroll
      for (int nt = 0; nt < 6; ++nt) {
        bf16x8 b = *reinterpret_cast<const bf16x8*>(
            &Wb[(nt * 16 + lrow) * ZLD + ks * 32 + lk8]);
        acc[0][nt] =
            __builtin_amdgcn_mfma_f32_16x16x32_bf16(a0, b, acc[0][nt], 0, 0, 0);
        acc[1][nt] =
            __builtin_amdgcn_mfma_f32_16x16x32_bf16(a1, b, acc[1][nt], 0, 0, 0);
      }
    }

    // ---- epilogue: row-dot in C layout (col=lane&15, row=(lane>>4)*4+reg) --
#pragma unroll
    for (int mt = 0; mt < 2; ++mt) {
      int rbase = wave * 32 + mt * 16 + lq * 4;
#pragma unroll
      for (int i = 0; i < 4; ++i) {
        int row = rbase + i;
        float s = 0.f;
#pragma unroll
        for (int nt = 0; nt < 6; ++nt) {
          float zv = bf2f(Zb[row * ZLD + nt * 16 + lrow]);
          s += acc[mt][nt][i] * zv;
        }
        dotacc[mt][i] += s;
      }
    }
    __syncthreads();
  }

#pragma unroll
  for (int mt = 0; mt < 2; ++mt)
#pragma unroll
    for (int i = 0; i < 4; ++i) {
      float v = dotacc[mt][i];
      v += __shfl_xor(v, 1);
      v += __shfl_xor(v, 2);
      v += __shfl_xor(v, 4);
      v += __shfl_xor(v, 8);
      dotacc[mt][i] = v;
    }
  if (lrow == 0) {
#pragma unroll
    for (int mt = 0; mt < 2; ++mt) {
      int row = wave * 32 + mt * 16 + lq * 4;
      float4 o = {dotacc[mt][0], dotacc[mt][1], dotacc[mt][2], dotacc[mt][3]};
      *reinterpret_cast<float4*>(
          &partial[(size_t)blockIdx.y * 4096 + n0 + row]) = o;
    }
  }
}

// ---------------------------------------------------------------------------
// Kernel 3: out[n] = sum_ft partial[ft][n] - sum_f logdet[f] + log(n1/n2)
// ---------------------------------------------------------------------------
__global__ __launch_bounds__(256) void finalize_kernel(
    const float* __restrict__ partial, const float* __restrict__ logdet,
    const int* __restrict__ n1p, const int* __restrict__ n2p,
    float* __restrict__ out) {
  __shared__ float red[256];
  const int t = threadIdx.x;
  red[t] = logdet[t];
  __syncthreads();
  for (int s = 128; s > 0; s >>= 1) {
    if (t < s) red[t] += red[t + s];
    __syncthreads();
  }
  const float S = red[0];
  const int n = blockIdx.x * 256 + t;
  float acc = 0.f;
#pragma unroll
  for (int ft = 0; ft < 16; ++ft) acc += partial[ft * 4096 + n];
  const float cst = logf((float)(*n1p) / (float)(*n2p));
  out[n] = acc - S + cst;
}

// ---------------------------------------------------------------------------
extern "C" void kernel_launch(void* const* d_in, const int* in_sizes, int n_in,
                              void* d_out, int out_size, void* d_ws,
                              size_t ws_size, hipStream_t stream) {
  const float* z  = (const float*)d_in[0];
  const float* s1 = (const float*)d_in[1];
  // d_in[2] = sigma_2 (unused by the reference)
  const float* w  = (const float*)d_in[3];
  const int* n1   = (const int*)d_in[4];
  const int* n2   = (const int*)d_in[5];
  float* out      = (float*)d_out;

  char* ws = (char*)d_ws;
  float* partial = (float*)ws;                 // 16*4096*4 = 262,144 B
  float* logdet  = (float*)(ws + 262144);      // 256*4     =   1,024 B

  det_kernel<<<dim3(256), dim3(64), 0, stream>>>(w, s1, logdet);
  quad_kernel<<<dim3(32, 16), dim3(256), 0, stream>>>(z, w, partial);
  finalize_kernel<<<dim3(16), dim3(256), 0, stream>>>(partial, logdet, n1, n2,
                                                      out);
}

// Round 2
// 761.301 us; speedup vs baseline: 1.1487x; 1.0455x over previous
//
#include <hip/hip_runtime.h>

// ---------------------------------------------------------------------------
// out[n] = sum_f ( z_nf^T W_f z_nf - log(clip(det(W_f S1_f + I),1e-5,1e5)) )
//          + log(n1/n2)
// N=4096, K=256, P2=96
//
// R5: det_kernel LU switched to THRESHOLD pivoting:
//  - row permutation doesn't change det (sign tracked) -> pivot search is
//    numerically optional. Common path: broadcast pv read + rcp + batched
//    group update + ONE barrier per step. No shuffle butterfly, no swap.
//  - rare fallback (|pv| < 1e-3, expected ~5-10 times over 24576 steps):
//    R4's packed-key argmax + physical swap, then retry the step once.
//  - accepted pivots >= 1e-3 with ~10-scale entries bound growth <= 1e4
//    -> logdet rel err <= ~1e-3, negligible vs bf16-quad error budget.
// quad/finalize unchanged (quad at HBM floor ~110 us).
// ---------------------------------------------------------------------------

typedef __attribute__((ext_vector_type(8))) short bf16x8;
typedef __attribute__((ext_vector_type(4))) float f32x4;

__device__ __forceinline__ unsigned short f2bf(float x) {
  unsigned int u = __builtin_bit_cast(unsigned int, x);
  u += 0x7fffu + ((u >> 16) & 1u);   // round-to-nearest-even
  return (unsigned short)(u >> 16);
}
__device__ __forceinline__ float bf2f(unsigned short h) {
  unsigned int u = ((unsigned int)h) << 16;
  return __builtin_bit_cast(float, u);
}

// ---------------------------------------------------------------------------
// Kernel 1: per-frequency logdet, one wave per frequency.
// ---------------------------------------------------------------------------
#define ALD 100   // Al row stride (dwords); 100 % 32 == 4 -> uniform b128 banks
#define WLD 35    // Wc row stride; 12*35 % 32 == 4 -> GEMM W-reads spread banks

__global__ __launch_bounds__(64) void det_kernel(
    const float* __restrict__ W, const float* __restrict__ S1,
    float* __restrict__ logdet) {
  __shared__ alignas(16) float Al[96 * ALD];   // 38,400 B
  __shared__ alignas(16) float Wc[96 * WLD];   // 13,440 B
  __shared__ alignas(16) float Sc[32 * 100];   // 12,800 B   (total 64,640 B)

  const int lane = threadIdx.x;
  const int f = blockIdx.x;
  const float* Wg = W + (size_t)f * 9216;
  const float* Sg = S1 + (size_t)f * 9216;

  const int i0 = (lane >> 3) * 12;   // lane tile: rows i0..i0+11
  const int j0 = (lane & 7) * 12;    //            cols j0..j0+11

  float acc[12][12];
#pragma unroll
  for (int a = 0; a < 12; ++a)
#pragma unroll
    for (int b = 0; b < 12; ++b) acc[a][b] = 0.f;

  for (int kc = 0; kc < 3; ++kc) {
    // stage Wc[i][kk] = W[i][kc*32+kk]  (768 float4 loads, b32 scatter)
#pragma unroll
    for (int it = 0; it < 12; ++it) {
      int c = lane + it * 64;          // 0..767
      int i = c >> 3;
      int k4 = (c & 7) << 2;
      const float4 v =
          *reinterpret_cast<const float4*>(Wg + i * 96 + kc * 32 + k4);
      Wc[i * WLD + k4 + 0] = v.x;
      Wc[i * WLD + k4 + 1] = v.y;
      Wc[i * WLD + k4 + 2] = v.z;
      Wc[i * WLD + k4 + 3] = v.w;
    }
    // stage Sc[kk][j] = S1[kc*32+kk][j]  (768 float4, b128 stores)
#pragma unroll
    for (int it = 0; it < 12; ++it) {
      int c = lane + it * 64;
      int kk = c / 24;
      int j4 = (c % 24) << 2;
      const float4 v =
          *reinterpret_cast<const float4*>(Sg + (kc * 32 + kk) * 96 + j4);
      *reinterpret_cast<float4*>(&Sc[kk * 100 + j4]) = v;
    }
    __syncthreads();
#pragma unroll 2
    for (int kk = 0; kk < 32; ++kk) {
      float wv[12];
#pragma unroll
      for (int r = 0; r < 12; ++r) wv[r] = Wc[(i0 + r) * WLD + kk];
      float sv[12];
      const float4 s0 = *reinterpret_cast<const float4*>(&Sc[kk * 100 + j0]);
      const float4 s1 =
          *reinterpret_cast<const float4*>(&Sc[kk * 100 + j0 + 4]);
      const float4 s2 =
          *reinterpret_cast<const float4*>(&Sc[kk * 100 + j0 + 8]);
      sv[0] = s0.x; sv[1] = s0.y; sv[2] = s0.z; sv[3] = s0.w;
      sv[4] = s1.x; sv[5] = s1.y; sv[6] = s1.z; sv[7] = s1.w;
      sv[8] = s2.x; sv[9] = s2.y; sv[10] = s2.z; sv[11] = s2.w;
#pragma unroll
      for (int a = 0; a < 12; ++a)
#pragma unroll
        for (int b = 0; b < 12; ++b) acc[a][b] += wv[a] * sv[b];
    }
    __syncthreads();
  }

  // Al = acc + I
#pragma unroll
  for (int a = 0; a < 12; ++a) {
    int i = i0 + a;
#pragma unroll
    for (int c4 = 0; c4 < 3; ++c4) {
      float4 v;
      v.x = acc[a][c4 * 4 + 0] + ((i == j0 + c4 * 4 + 0) ? 1.f : 0.f);
      v.y = acc[a][c4 * 4 + 1] + ((i == j0 + c4 * 4 + 1) ? 1.f : 0.f);
      v.z = acc[a][c4 * 4 + 2] + ((i == j0 + c4 * 4 + 2) ? 1.f : 0.f);
      v.w = acc[a][c4 * 4 + 3] + ((i == j0 + c4 * 4 + 3) ? 1.f : 0.f);
      *reinterpret_cast<float4*>(&Al[i * ALD + j0 + c4 * 4]) = v;
    }
  }
  __syncthreads();

  // ---- LU with THRESHOLD pivoting, single wave, one barrier per step ----
  int sgn = 0;
  for (int k = 0; k < 95; ++k) {
    const int rowk = k * ALD;
    const int li0 = k + 1 + lane;
    const bool h0 = li0 < 96;
    const int li1 = k + 65 + lane;
    const bool h1 = (k < 31) && (li1 < 96);

    float pv, L0n, L1n;
    int tried = 0;
    for (;;) {
      pv = Al[rowk + k];                         // broadcast read (uniform)
      L0n = h0 ? Al[li0 * ALD + k] : 0.f;
      L1n = h1 ? Al[li1 * ALD + k] : 0.f;
      if (fabsf(pv) >= 1e-3f || tried) break;    // uniform branch
      tried = 1;
      // --- RARE fallback: packed-key argmax over col k, physical swap ---
      const int i0r = k + lane;
      const int i1r = k + 64 + lane;
      const float c0 = (i0r < 96) ? Al[i0r * ALD + k] : 0.f;
      const float c1 = (i1r < 96) ? Al[i1r * ALD + k] : 0.f;
      const float a0 = fabsf(c0), a1 = fabsf(c1);
      float bav = a0;
      unsigned bslot = 0u;
      if (a1 > a0) { bav = a1; bslot = 64u; }
      unsigned key = (__float_as_uint(bav) & ~127u) | bslot | (unsigned)lane;
#pragma unroll
      for (int m = 1; m < 64; m <<= 1) {
        unsigned o = (unsigned)__shfl_xor((int)key, m);
        key = key > o ? key : o;
      }
      const int wl = (int)(key & 63u);
      const int slot = (int)((key >> 6) & 1u);
      const int bi = k + slot * 64 + wl;
      if (bi == k) break;                        // pv already the column max
      sgn ^= 1;
      if (lane < 24) {
        const int c = lane;                      // chunk 0..23, cols 4c..4c+3
        if (k <= c * 4 + 3) {                    // live chunks only
          float4 x = *reinterpret_cast<float4*>(&Al[k * ALD + c * 4]);
          float4 y = *reinterpret_cast<float4*>(&Al[bi * ALD + c * 4]);
          *reinterpret_cast<float4*>(&Al[k * ALD + c * 4]) = y;
          *reinterpret_cast<float4*>(&Al[bi * ALD + c * 4]) = x;
        }
      }
      __syncthreads();                           // uniform path, single wave
      // loop: re-read pv / numerators, then proceed
    }

    const float rpv = __builtin_amdgcn_rcpf(pv); // ~1ulp; fine for logdet
    const float L0 = L0n * rpv;
    const float L1 = L1n * rpv;
    const int gfirst = k >> 5;

#pragma unroll
    for (int g = 0; g < 3; ++g) {
      if (g >= gfirst) {   // group holds live columns (wave-uniform)
        float4 p[8];
#pragma unroll
        for (int c = 0; c < 8; ++c)
          p[c] = *reinterpret_cast<const float4*>(
              &Al[rowk + (g * 8 + c) * 4]);
        if (h0) {
          const int rb = li0 * ALD;
#pragma unroll
          for (int c = 0; c < 8; ++c) {
            float4 a = *reinterpret_cast<float4*>(&Al[rb + (g * 8 + c) * 4]);
            a.x -= L0 * p[c].x;
            a.y -= L0 * p[c].y;
            a.z -= L0 * p[c].z;
            a.w -= L0 * p[c].w;
            *reinterpret_cast<float4*>(&Al[rb + (g * 8 + c) * 4]) = a;
          }
        }
        if (h1) {
          const int rb = li1 * ALD;
#pragma unroll
          for (int c = 0; c < 8; ++c) {
            float4 a = *reinterpret_cast<float4*>(&Al[rb + (g * 8 + c) * 4]);
            a.x -= L1 * p[c].x;
            a.y -= L1 * p[c].y;
            a.z -= L1 * p[c].z;
            a.w -= L1 * p[c].w;
            *reinterpret_cast<float4*>(&Al[rb + (g * 8 + c) * 4]) = a;
          }
        }
      }
    }
    __syncthreads();   // single sync point: orders writes vs next-step reads
  }

  // logdet from U diagonal
  float ls = 0.f;
  int neg = 0;
  for (int kk = lane; kk < 96; kk += 64) {
    float v = Al[kk * ALD + kk];
    ls += logf(fabsf(v));
    if (v < 0.f) neg ^= 1;
  }
#pragma unroll
  for (int m = 1; m < 64; m <<= 1) {
    ls += __shfl_xor(ls, m);
    neg ^= __shfl_xor(neg, m);
  }
  if (lane == 0) {
    const float LMIN = -11.5129254f, LMAX = 11.5129254f;  // log(1e-5), log(1e5)
    float c;
    if (neg ^ sgn) c = LMIN;              // det <= 0 -> clipped to 1e-5
    else c = fminf(fmaxf(ls, LMIN), LMAX);
    logdet[f] = c;
  }
}

// ---------------------------------------------------------------------------
// Kernel 2: quad[n,f] via bf16 MFMA (unchanged — passed, ~110 us, HBM floor).
// ---------------------------------------------------------------------------
#define ZLD 104

__global__ __launch_bounds__(256) void quad_kernel(
    const float* __restrict__ z, const float* __restrict__ W,
    float* __restrict__ partial) {
  __shared__ alignas(16) unsigned short Zb[128 * ZLD];
  __shared__ alignas(16) unsigned short Wb[96 * ZLD];

  const int tid = threadIdx.x;
  const int lane = tid & 63, wave = tid >> 6;
  const int n0 = blockIdx.x * 128;
  const int f0 = blockIdx.y * 16;
  const int lrow = lane & 15;
  const int lq = lane >> 4;
  const int lk8 = lq * 8;
  const int rgrp = tid >> 3;   // 0..31
  const int cgrp = tid & 7;    // 0..7

  float dotacc[2][4];
#pragma unroll
  for (int mt = 0; mt < 2; ++mt)
#pragma unroll
    for (int i = 0; i < 4; ++i) dotacc[mt][i] = 0.f;

  for (int ff = 0; ff < 16; ++ff) {
    const int f = f0 + ff;
    // ---- stage z tile: 8 threads/row, contiguous wave segments ----
#pragma unroll
    for (int p = 0; p < 4; ++p) {
      int r = p * 32 + rgrp;
      const float4* src = reinterpret_cast<const float4*>(
          z + (size_t)(n0 + r) * 24576 + (size_t)f * 96);
#pragma unroll
      for (int cc = 0; cc < 3; ++cc) {
        int c = cgrp + cc * 8;           // 0..23
        float4 d = src[c];
        ushort4 s;
        s.x = f2bf(d.x); s.y = f2bf(d.y); s.z = f2bf(d.z); s.w = f2bf(d.w);
        *reinterpret_cast<ushort4*>(&Zb[r * ZLD + c * 4]) = s;
      }
    }
    // ---- stage W rows (natural layout): 2304 float4, 9 per thread ----
    const float4* wsrc =
        reinterpret_cast<const float4*>(W + (size_t)f * 9216);
#pragma unroll
    for (int it = 0; it < 9; ++it) {
      int c = tid + it * 256;            // 0..2303
      int k = c / 24, q4 = (c % 24) << 2;
      float4 d = wsrc[c];
      ushort4 s;
      s.x = f2bf(d.x); s.y = f2bf(d.y); s.z = f2bf(d.z); s.w = f2bf(d.w);
      *reinterpret_cast<ushort4*>(&Wb[k * ZLD + q4]) = s;
    }
    __syncthreads();

    // ---- MFMA: Y(128x96) = Z @ W^T; wave handles 32 rows ----
    f32x4 acc[2][6];
#pragma unroll
    for (int mt = 0; mt < 2; ++mt)
#pragma unroll
      for (int nt = 0; nt < 6; ++nt) acc[mt][nt] = (f32x4){0.f, 0.f, 0.f, 0.f};

#pragma unroll
    for (int ks = 0; ks < 3; ++ks) {
      bf16x8 a0 = *reinterpret_cast<const bf16x8*>(
          &Zb[(wave * 32 + lrow) * ZLD + ks * 32 + lk8]);
      bf16x8 a1 = *reinterpret_cast<const bf16x8*>(
          &Zb[(wave * 32 + 16 + lrow) * ZLD + ks * 32 + lk8]);
#pragma unroll
      for (int nt = 0; nt < 6; ++nt) {
        bf16x8 b = *reinterpret_cast<const bf16x8*>(
            &Wb[(nt * 16 + lrow) * ZLD + ks * 32 + lk8]);
        acc[0][nt] =
            __builtin_amdgcn_mfma_f32_16x16x32_bf16(a0, b, acc[0][nt], 0, 0, 0);
        acc[1][nt] =
            __builtin_amdgcn_mfma_f32_16x16x32_bf16(a1, b, acc[1][nt], 0, 0, 0);
      }
    }

    // ---- epilogue: row-dot in C layout (col=lane&15, row=(lane>>4)*4+reg) --
#pragma unroll
    for (int mt = 0; mt < 2; ++mt) {
      int rbase = wave * 32 + mt * 16 + lq * 4;
#pragma unroll
      for (int i = 0; i < 4; ++i) {
        int row = rbase + i;
        float s = 0.f;
#pragma unroll
        for (int nt = 0; nt < 6; ++nt) {
          float zv = bf2f(Zb[row * ZLD + nt * 16 + lrow]);
          s += acc[mt][nt][i] * zv;
        }
        dotacc[mt][i] += s;
      }
    }
    __syncthreads();
  }

#pragma unroll
  for (int mt = 0; mt < 2; ++mt)
#pragma unroll
    for (int i = 0; i < 4; ++i) {
      float v = dotacc[mt][i];
      v += __shfl_xor(v, 1);
      v += __shfl_xor(v, 2);
      v += __shfl_xor(v, 4);
      v += __shfl_xor(v, 8);
      dotacc[mt][i] = v;
    }
  if (lrow == 0) {
#pragma unroll
    for (int mt = 0; mt < 2; ++mt) {
      int row = wave * 32 + mt * 16 + lq * 4;
      float4 o = {dotacc[mt][0], dotacc[mt][1], dotacc[mt][2], dotacc[mt][3]};
      *reinterpret_cast<float4*>(
          &partial[(size_t)blockIdx.y * 4096 + n0 + row]) = o;
    }
  }
}

// ---------------------------------------------------------------------------
// Kernel 3: out[n] = sum_ft partial[ft][n] - sum_f logdet[f] + log(n1/n2)
// ---------------------------------------------------------------------------
__global__ __launch_bounds__(256) void finalize_kernel(
    const float* __restrict__ partial, const float* __restrict__ logdet,
    const int* __restrict__ n1p, const int* __restrict__ n2p,
    float* __restrict__ out) {
  __shared__ float red[256];
  const int t = threadIdx.x;
  red[t] = logdet[t];
  __syncthreads();
  for (int s = 128; s > 0; s >>= 1) {
    if (t < s) red[t] += red[t + s];
    __syncthreads();
  }
  const float S = red[0];
  const int n = blockIdx.x * 256 + t;
  float acc = 0.f;
#pragma unroll
  for (int ft = 0; ft < 16; ++ft) acc += partial[ft * 4096 + n];
  const float cst = logf((float)(*n1p) / (float)(*n2p));
  out[n] = acc - S + cst;
}

// ---------------------------------------------------------------------------
extern "C" void kernel_launch(void* const* d_in, const int* in_sizes, int n_in,
                              void* d_out, int out_size, void* d_ws,
                              size_t ws_size, hipStream_t stream) {
  const float* z  = (const float*)d_in[0];
  const float* s1 = (const float*)d_in[1];
  // d_in[2] = sigma_2 (unused by the reference)
  const float* w  = (const float*)d_in[3];
  const int* n1   = (const int*)d_in[4];
  const int* n2   = (const int*)d_in[5];
  float* out      = (float*)d_out;

  char* ws = (char*)d_ws;
  float* partial = (float*)ws;                 // 16*4096*4 = 262,144 B
  float* logdet  = (float*)(ws + 262144);      // 256*4     =   1,024 B

  det_kernel<<<dim3(256), dim3(64), 0, stream>>>(w, s1, logdet);
  quad_kernel<<<dim3(32, 16), dim3(256), 0, stream>>>(z, w, partial);
  finalize_kernel<<<dim3(16), dim3(256), 0, stream>>>(partial, logdet, n1, n2,
                                                      out);
}

// Round 3
// 726.591 us; speedup vs baseline: 1.2036x; 1.0478x over previous
//
#include <hip/hip_runtime.h>

// ---------------------------------------------------------------------------
// out[n] = sum_f ( z_nf^T W_f z_nf - log(clip(det(W_f S1_f + I),1e-5,1e5)) )
//          + log(n1/n2)
// N=4096, K=256, P2=96
//
// R6: det_kernel LU -> BLOCKED right-looking LU, NB=8, single wave:
//  - panel fact (96x8) fully register-resident: per step only shuffles+FMA,
//    no LDS, no barriers. Threshold pivoting (|pv|>=1e-3), rare fallback
//    argmax + register/LDS row swap (trailing cols only; L-part swap is
//    irrelevant for det).
//  - U12 solve column-parallel in registers (28 shuffled L11 broadcasts).
//  - trailing rank-8 update: L21 in regs, U12 chunks via UNIFORM b128 reads
//    (broadcast, conflict-free) -> pure throughput, no per-step latency.
//  - U diagonal accumulated on the fly (pv is wave-uniform): no final
//    diag reads, no reduction.
//  - 3 barriers/panel (36 total) instead of 95+.
// quad/finalize unchanged (quad ~110 us, near HBM floor).
// ---------------------------------------------------------------------------

typedef __attribute__((ext_vector_type(8))) short bf16x8;
typedef __attribute__((ext_vector_type(4))) float f32x4;

__device__ __forceinline__ unsigned short f2bf(float x) {
  unsigned int u = __builtin_bit_cast(unsigned int, x);
  u += 0x7fffu + ((u >> 16) & 1u);   // round-to-nearest-even
  return (unsigned short)(u >> 16);
}
__device__ __forceinline__ float bf2f(unsigned short h) {
  unsigned int u = ((unsigned int)h) << 16;
  return __builtin_bit_cast(float, u);
}

// ---------------------------------------------------------------------------
// Kernel 1: per-frequency logdet, one wave per frequency.
// ---------------------------------------------------------------------------
#define ALD 100   // Al row stride (dwords); rows 16B-aligned
#define WLD 35    // Wc row stride

__global__ __launch_bounds__(64) void det_kernel(
    const float* __restrict__ W, const float* __restrict__ S1,
    float* __restrict__ logdet) {
  __shared__ alignas(16) float Al[96 * ALD];   // 38,400 B
  __shared__ alignas(16) float Wc[96 * WLD];   // 13,440 B
  __shared__ alignas(16) float Sc[32 * 100];   // 12,800 B   (total 64,640 B)

  const int lane = threadIdx.x;
  const int f = blockIdx.x;
  const float* Wg = W + (size_t)f * 9216;
  const float* Sg = S1 + (size_t)f * 9216;

  const int i0 = (lane >> 3) * 12;   // lane tile: rows i0..i0+11
  const int j0 = (lane & 7) * 12;    //            cols j0..j0+11

  float acc[12][12];
#pragma unroll
  for (int a = 0; a < 12; ++a)
#pragma unroll
    for (int b = 0; b < 12; ++b) acc[a][b] = 0.f;

  for (int kc = 0; kc < 3; ++kc) {
    // stage Wc[i][kk] = W[i][kc*32+kk]
#pragma unroll
    for (int it = 0; it < 12; ++it) {
      int c = lane + it * 64;          // 0..767
      int i = c >> 3;
      int k4 = (c & 7) << 2;
      const float4 v =
          *reinterpret_cast<const float4*>(Wg + i * 96 + kc * 32 + k4);
      Wc[i * WLD + k4 + 0] = v.x;
      Wc[i * WLD + k4 + 1] = v.y;
      Wc[i * WLD + k4 + 2] = v.z;
      Wc[i * WLD + k4 + 3] = v.w;
    }
    // stage Sc[kk][j] = S1[kc*32+kk][j]
#pragma unroll
    for (int it = 0; it < 12; ++it) {
      int c = lane + it * 64;
      int kk = c / 24;
      int j4 = (c % 24) << 2;
      const float4 v =
          *reinterpret_cast<const float4*>(Sg + (kc * 32 + kk) * 96 + j4);
      *reinterpret_cast<float4*>(&Sc[kk * 100 + j4]) = v;
    }
    __syncthreads();
#pragma unroll 2
    for (int kk = 0; kk < 32; ++kk) {
      float wv[12];
#pragma unroll
      for (int r = 0; r < 12; ++r) wv[r] = Wc[(i0 + r) * WLD + kk];
      float sv[12];
      const float4 s0 = *reinterpret_cast<const float4*>(&Sc[kk * 100 + j0]);
      const float4 s1 =
          *reinterpret_cast<const float4*>(&Sc[kk * 100 + j0 + 4]);
      const float4 s2 =
          *reinterpret_cast<const float4*>(&Sc[kk * 100 + j0 + 8]);
      sv[0] = s0.x; sv[1] = s0.y; sv[2] = s0.z; sv[3] = s0.w;
      sv[4] = s1.x; sv[5] = s1.y; sv[6] = s1.z; sv[7] = s1.w;
      sv[8] = s2.x; sv[9] = s2.y; sv[10] = s2.z; sv[11] = s2.w;
#pragma unroll
      for (int a = 0; a < 12; ++a)
#pragma unroll
        for (int b = 0; b < 12; ++b) acc[a][b] += wv[a] * sv[b];
    }
    __syncthreads();
  }

  // Al = acc + I
#pragma unroll
  for (int a = 0; a < 12; ++a) {
    int i = i0 + a;
#pragma unroll
    for (int c4 = 0; c4 < 3; ++c4) {
      float4 v;
      v.x = acc[a][c4 * 4 + 0] + ((i == j0 + c4 * 4 + 0) ? 1.f : 0.f);
      v.y = acc[a][c4 * 4 + 1] + ((i == j0 + c4 * 4 + 1) ? 1.f : 0.f);
      v.z = acc[a][c4 * 4 + 2] + ((i == j0 + c4 * 4 + 2) ? 1.f : 0.f);
      v.w = acc[a][c4 * 4 + 3] + ((i == j0 + c4 * 4 + 3) ? 1.f : 0.f);
      *reinterpret_cast<float4*>(&Al[i * ALD + j0 + c4 * 4]) = v;
    }
  }
  __syncthreads();

  // ======================= blocked LU, NB = 8 ==============================
  float ls = 0.f;    // sum log|U_jj|  (wave-uniform)
  int neg = 0;       // parity of negative U_jj (uniform)
  int sgn = 0;       // row-swap parity (uniform)

  for (int p = 0; p < 12; ++p) {
    const int c0 = p * 8;
    const int NC = 88 - c0;            // trailing cols
    const int NT = NC >> 2;            // trailing float4 chunks
    const bool e0 = lane <= 95 - c0;               // slot0 row exists
    const bool e1 = (c0 < 32) && (lane <= 31 - c0); // slot1 row exists

    // ---- load panel (rows c0.., cols c0..c0+7) into registers ----
    float P0[8], P1[8];
#pragma unroll
    for (int m = 0; m < 8; ++m) { P0[m] = 0.f; P1[m] = 0.f; }
    if (e0) {
      const float4 x =
          *reinterpret_cast<const float4*>(&Al[(c0 + lane) * ALD + c0]);
      const float4 y =
          *reinterpret_cast<const float4*>(&Al[(c0 + lane) * ALD + c0 + 4]);
      P0[0] = x.x; P0[1] = x.y; P0[2] = x.z; P0[3] = x.w;
      P0[4] = y.x; P0[5] = y.y; P0[6] = y.z; P0[7] = y.w;
    }
    if (e1) {
      const float4 x =
          *reinterpret_cast<const float4*>(&Al[(c0 + 64 + lane) * ALD + c0]);
      const float4 y =
          *reinterpret_cast<const float4*>(&Al[(c0 + 64 + lane) * ALD + c0 + 4]);
      P1[0] = x.x; P1[1] = x.y; P1[2] = x.z; P1[3] = x.w;
      P1[4] = y.x; P1[5] = y.y; P1[6] = y.z; P1[7] = y.w;
    }

    // ---- panel factorization: 8 register-resident steps ----
#pragma unroll
    for (int j = 0; j < 8; ++j) {
      const int jc = c0 + j;
      float pv;
      int tried = 0;
      for (;;) {
        pv = __shfl(P0[j], j);
        if (fabsf(pv) >= 1e-3f || tried) break;   // uniform branch
        tried = 1;
        // rare fallback: argmax over col j, rows >= jc
        unsigned k0 = (e0 && lane >= j)
                          ? ((__float_as_uint(fabsf(P0[j])) & ~127u) |
                             (unsigned)lane)
                          : 0u;
        unsigned k1 = e1 ? ((__float_as_uint(fabsf(P1[j])) & ~127u) | 64u |
                            (unsigned)lane)
                         : 0u;
        unsigned key = k0 > k1 ? k0 : k1;
#pragma unroll
        for (int m = 1; m < 64; m <<= 1) {
          unsigned o = (unsigned)__shfl_xor((int)key, m);
          key = key > o ? key : o;
        }
        const int wl = (int)(key & 63u);
        const int slot = (int)((key >> 6) & 1u);
        const int bi = c0 + slot * 64 + wl;
        if (bi <= jc) break;                      // already max / degenerate
        sgn ^= 1;
        // swap panel registers rows jc <-> bi
#pragma unroll
        for (int m = 0; m < 8; ++m) {
          const float vj = __shfl(P0[m], j);
          const float vb0 = __shfl(P0[m], wl);
          const float vb1 = __shfl(P1[m], wl);
          const float vb = slot ? vb1 : vb0;
          if (lane == j) P0[m] = vb;
          if (lane == wl) {
            if (slot) P1[m] = vj;
            else P0[m] = vj;
          }
        }
        // swap trailing cols in LDS (cols >= c0+8); L-part not needed
        if (lane < NT) {
          const int col0 = c0 + 8 + lane * 4;
          float4 xx = *reinterpret_cast<float4*>(&Al[jc * ALD + col0]);
          float4 yy = *reinterpret_cast<float4*>(&Al[bi * ALD + col0]);
          *reinterpret_cast<float4*>(&Al[jc * ALD + col0]) = yy;
          *reinterpret_cast<float4*>(&Al[bi * ALD + col0]) = xx;
        }
        // retry: re-broadcast pv
      }
      const float rpv = __builtin_amdgcn_rcpf(pv);
      const bool up0 = e0 && (lane > j);
      const float L0 = P0[j] * rpv;
      const float L1 = P1[j] * rpv;
      if (up0) P0[j] = L0;
      if (e1) P1[j] = L1;
#pragma unroll
      for (int jj = j + 1; jj < 8; ++jj) {
        const float u = __shfl(P0[jj], j);
        if (up0) P0[jj] -= L0 * u;
        if (e1) P1[jj] -= L1 * u;
      }
      ls += logf(fabsf(pv));
      if (pv < 0.f) neg ^= 1;
    }
    __syncthreads();   // order fallback LDS swaps vs solve/trailing

    if (NC > 0) {
      // ---- U12 solve: X = L11^{-1} A12, column-parallel ----
      const int ca = c0 + 8 + lane;
      const bool va = lane < NC;
      const int cb = ca + 64;
      const bool vb = (lane + 64) < NC;
      float a[8], b[8];
#pragma unroll
      for (int i = 0; i < 8; ++i) {
        a[i] = va ? Al[(c0 + i) * ALD + ca] : 0.f;
        b[i] = vb ? Al[(c0 + i) * ALD + cb] : 0.f;
      }
#pragma unroll
      for (int jj = 1; jj < 8; ++jj)
#pragma unroll
        for (int i = 0; i < jj; ++i) {
          const float Lv = __shfl(P0[i], jj);   // L11[jj][i]
          a[jj] -= Lv * a[i];
          b[jj] -= Lv * b[i];
        }
#pragma unroll
      for (int i = 0; i < 8; ++i) {
        if (va) Al[(c0 + i) * ALD + ca] = a[i];
        if (vb) Al[(c0 + i) * ALD + cb] = b[i];
      }
      __syncthreads();   // U12 visible before trailing reads

      // ---- trailing rank-8 update: C -= L21 (regs) * U12 (uniform LDS) ----
      const bool r0v = e0 && (lane >= 8);
      const bool r1v = e1;
      const int r0 = (c0 + lane) * ALD;
      const int r1 = (c0 + 64 + lane) * ALD;
      for (int ct = 0; ct < NT; ++ct) {
        const int col0 = c0 + 8 + ct * 4;
        float4 u[8];
#pragma unroll
        for (int i = 0; i < 8; ++i)
          u[i] = *reinterpret_cast<const float4*>(&Al[(c0 + i) * ALD + col0]);
        if (r0v) {
          float4 x = *reinterpret_cast<float4*>(&Al[r0 + col0]);
#pragma unroll
          for (int i = 0; i < 8; ++i) {
            x.x -= P0[i] * u[i].x;
            x.y -= P0[i] * u[i].y;
            x.z -= P0[i] * u[i].z;
            x.w -= P0[i] * u[i].w;
          }
          *reinterpret_cast<float4*>(&Al[r0 + col0]) = x;
        }
        if (r1v) {
          float4 x = *reinterpret_cast<float4*>(&Al[r1 + col0]);
#pragma unroll
          for (int i = 0; i < 8; ++i) {
            x.x -= P1[i] * u[i].x;
            x.y -= P1[i] * u[i].y;
            x.z -= P1[i] * u[i].z;
            x.w -= P1[i] * u[i].w;
          }
          *reinterpret_cast<float4*>(&Al[r1 + col0]) = x;
        }
      }
    }
    __syncthreads();   // next panel's loads see this panel's updates
  }

  if (lane == 0) {
    const float LMIN = -11.5129254f, LMAX = 11.5129254f;  // log(1e-5), log(1e5)
    float c;
    if (neg ^ sgn) c = LMIN;              // det <= 0 -> clipped to 1e-5
    else c = fminf(fmaxf(ls, LMIN), LMAX);
    logdet[f] = c;
  }
}

// ---------------------------------------------------------------------------
// Kernel 2: quad[n,f] via bf16 MFMA (unchanged — passed, ~110 us, HBM floor).
// ---------------------------------------------------------------------------
#define ZLD 104

__global__ __launch_bounds__(256) void quad_kernel(
    const float* __restrict__ z, const float* __restrict__ W,
    float* __restrict__ partial) {
  __shared__ alignas(16) unsigned short Zb[128 * ZLD];
  __shared__ alignas(16) unsigned short Wb[96 * ZLD];

  const int tid = threadIdx.x;
  const int lane = tid & 63, wave = tid >> 6;
  const int n0 = blockIdx.x * 128;
  const int f0 = blockIdx.y * 16;
  const int lrow = lane & 15;
  const int lq = lane >> 4;
  const int lk8 = lq * 8;
  const int rgrp = tid >> 3;   // 0..31
  const int cgrp = tid & 7;    // 0..7

  float dotacc[2][4];
#pragma unroll
  for (int mt = 0; mt < 2; ++mt)
#pragma unroll
    for (int i = 0; i < 4; ++i) dotacc[mt][i] = 0.f;

  for (int ff = 0; ff < 16; ++ff) {
    const int f = f0 + ff;
    // ---- stage z tile: 8 threads/row, contiguous wave segments ----
#pragma unroll
    for (int p = 0; p < 4; ++p) {
      int r = p * 32 + rgrp;
      const float4* src = reinterpret_cast<const float4*>(
          z + (size_t)(n0 + r) * 24576 + (size_t)f * 96);
#pragma unroll
      for (int cc = 0; cc < 3; ++cc) {
        int c = cgrp + cc * 8;           // 0..23
        float4 d = src[c];
        ushort4 s;
        s.x = f2bf(d.x); s.y = f2bf(d.y); s.z = f2bf(d.z); s.w = f2bf(d.w);
        *reinterpret_cast<ushort4*>(&Zb[r * ZLD + c * 4]) = s;
      }
    }
    // ---- stage W rows (natural layout): 2304 float4, 9 per thread ----
    const float4* wsrc =
        reinterpret_cast<const float4*>(W + (size_t)f * 9216);
#pragma unroll
    for (int it = 0; it < 9; ++it) {
      int c = tid + it * 256;            // 0..2303
      int k = c / 24, q4 = (c % 24) << 2;
      float4 d = wsrc[c];
      ushort4 s;
      s.x = f2bf(d.x); s.y = f2bf(d.y); s.z = f2bf(d.z); s.w = f2bf(d.w);
      *reinterpret_cast<ushort4*>(&Wb[k * ZLD + q4]) = s;
    }
    __syncthreads();

    // ---- MFMA: Y(128x96) = Z @ W^T; wave handles 32 rows ----
    f32x4 acc[2][6];
#pragma unroll
    for (int mt = 0; mt < 2; ++mt)
#pragma unroll
      for (int nt = 0; nt < 6; ++nt) acc[mt][nt] = (f32x4){0.f, 0.f, 0.f, 0.f};

#pragma unroll
    for (int ks = 0; ks < 3; ++ks) {
      bf16x8 a0 = *reinterpret_cast<const bf16x8*>(
          &Zb[(wave * 32 + lrow) * ZLD + ks * 32 + lk8]);
      bf16x8 a1 = *reinterpret_cast<const bf16x8*>(
          &Zb[(wave * 32 + 16 + lrow) * ZLD + ks * 32 + lk8]);
#pragma unroll
      for (int nt = 0; nt < 6; ++nt) {
        bf16x8 b = *reinterpret_cast<const bf16x8*>(
            &Wb[(nt * 16 + lrow) * ZLD + ks * 32 + lk8]);
        acc[0][nt] =
            __builtin_amdgcn_mfma_f32_16x16x32_bf16(a0, b, acc[0][nt], 0, 0, 0);
        acc[1][nt] =
            __builtin_amdgcn_mfma_f32_16x16x32_bf16(a1, b, acc[1][nt], 0, 0, 0);
      }
    }

    // ---- epilogue: row-dot in C layout (col=lane&15, row=(lane>>4)*4+reg) --
#pragma unroll
    for (int mt = 0; mt < 2; ++mt) {
      int rbase = wave * 32 + mt * 16 + lq * 4;
#pragma unroll
      for (int i = 0; i < 4; ++i) {
        int row = rbase + i;
        float s = 0.f;
#pragma unroll
        for (int nt = 0; nt < 6; ++nt) {
          float zv = bf2f(Zb[row * ZLD + nt * 16 + lrow]);
          s += acc[mt][nt][i] * zv;
        }
        dotacc[mt][i] += s;
      }
    }
    __syncthreads();
  }

#pragma unroll
  for (int mt = 0; mt < 2; ++mt)
#pragma unroll
    for (int i = 0; i < 4; ++i) {
      float v = dotacc[mt][i];
      v += __shfl_xor(v, 1);
      v += __shfl_xor(v, 2);
      v += __shfl_xor(v, 4);
      v += __shfl_xor(v, 8);
      dotacc[mt][i] = v;
    }
  if (lrow == 0) {
#pragma unroll
    for (int mt = 0; mt < 2; ++mt) {
      int row = wave * 32 + mt * 16 + lq * 4;
      float4 o = {dotacc[mt][0], dotacc[mt][1], dotacc[mt][2], dotacc[mt][3]};
      *reinterpret_cast<float4*>(
          &partial[(size_t)blockIdx.y * 4096 + n0 + row]) = o;
    }
  }
}

// ---------------------------------------------------------------------------
// Kernel 3: out[n] = sum_ft partial[ft][n] - sum_f logdet[f] + log(n1/n2)
// ---------------------------------------------------------------------------
__global__ __launch_bounds__(256) void finalize_kernel(
    const float* __restrict__ partial, const float* __restrict__ logdet,
    const int* __restrict__ n1p, const int* __restrict__ n2p,
    float* __restrict__ out) {
  __shared__ float red[256];
  const int t = threadIdx.x;
  red[t] = logdet[t];
  __syncthreads();
  for (int s = 128; s > 0; s >>= 1) {
    if (t < s) red[t] += red[t + s];
    __syncthreads();
  }
  const float S = red[0];
  const int n = blockIdx.x * 256 + t;
  float acc = 0.f;
#pragma unroll
  for (int ft = 0; ft < 16; ++ft) acc += partial[ft * 4096 + n];
  const float cst = logf((float)(*n1p) / (float)(*n2p));
  out[n] = acc - S + cst;
}

// ---------------------------------------------------------------------------
extern "C" void kernel_launch(void* const* d_in, const int* in_sizes, int n_in,
                              void* d_out, int out_size, void* d_ws,
                              size_t ws_size, hipStream_t stream) {
  const float* z  = (const float*)d_in[0];
  const float* s1 = (const float*)d_in[1];
  // d_in[2] = sigma_2 (unused by the reference)
  const float* w  = (const float*)d_in[3];
  const int* n1   = (const int*)d_in[4];
  const int* n2   = (const int*)d_in[5];
  float* out      = (float*)d_out;

  char* ws = (char*)d_ws;
  float* partial = (float*)ws;                 // 16*4096*4 = 262,144 B
  float* logdet  = (float*)(ws + 262144);      // 256*4     =   1,024 B

  det_kernel<<<dim3(256), dim3(64), 0, stream>>>(w, s1, logdet);
  quad_kernel<<<dim3(32, 16), dim3(256), 0, stream>>>(z, w, partial);
  finalize_kernel<<<dim3(16), dim3(256), 0, stream>>>(partial, logdet, n1, n2,
                                                      out);
}

// Round 4
// 661.170 us; speedup vs baseline: 1.3227x; 1.0989x over previous
//
#include <hip/hip_runtime.h>

// ---------------------------------------------------------------------------
// out[n] = sum_f ( z_nf^T W_f z_nf - log(clip(det(W_f S1_f + I),1e-5,1e5)) )
//          + log(n1/n2)
// N=4096, K=256, P2=96
//
// R7: FUSE det + quad into one dispatch (they are data-independent):
//  - blocks 0..255   : det for f=blockIdx.x, single wave (threads>=64 exit).
//    det is latency-bound (1 wave/CU); quad is HBM-bound -> det hides under
//    quad's memory stalls instead of serializing 105+110 us.
//  - blocks 256..767 : quad tile (identical math to R6's quad_kernel).
//  - det's __syncthreads replaced by compiler fences: single-wave LDS is
//    in-order per the DS pipe (cross-lane write->read visible in program
//    order), so no hardware barrier needed; also sidesteps exited-wave
//    barrier semantics.
//  - shared LDS union: det 64,640 B vs quad 46,592 B -> 64,640 B/block,
//    2 blocks/CU.
// finalize unchanged.
// ---------------------------------------------------------------------------

typedef __attribute__((ext_vector_type(8))) short bf16x8;
typedef __attribute__((ext_vector_type(4))) float f32x4;

#define WFENCE() asm volatile("" ::: "memory")

__device__ __forceinline__ unsigned short f2bf(float x) {
  unsigned int u = __builtin_bit_cast(unsigned int, x);
  u += 0x7fffu + ((u >> 16) & 1u);   // round-to-nearest-even
  return (unsigned short)(u >> 16);
}
__device__ __forceinline__ float bf2f(unsigned short h) {
  unsigned int u = ((unsigned int)h) << 16;
  return __builtin_bit_cast(float, u);
}

#define ALD 100   // Al row stride (dwords)
#define WLD 35    // Wc row stride
#define ZLD 104

// ---------------------------------------------------------------------------
// det body: one wave, barrier-free (single-wave LDS is in-order).
// smem layout: Al[0..9600) Wc[9600..12960) Sc[12960..16160)  (floats)
// ---------------------------------------------------------------------------
__device__ __forceinline__ void det_body(const int lane, const int f,
                                         const float* __restrict__ W,
                                         const float* __restrict__ S1,
                                         float* __restrict__ logdet,
                                         float* smem) {
  float* Al = smem;
  float* Wc = smem + 9600;
  float* Sc = smem + 12960;

  const float* Wg = W + (size_t)f * 9216;
  const float* Sg = S1 + (size_t)f * 9216;

  const int i0 = (lane >> 3) * 12;
  const int j0 = (lane & 7) * 12;

  float acc[12][12];
#pragma unroll
  for (int a = 0; a < 12; ++a)
#pragma unroll
    for (int b = 0; b < 12; ++b) acc[a][b] = 0.f;

  for (int kc = 0; kc < 3; ++kc) {
#pragma unroll
    for (int it = 0; it < 12; ++it) {
      int c = lane + it * 64;          // 0..767
      int i = c >> 3;
      int k4 = (c & 7) << 2;
      const float4 v =
          *reinterpret_cast<const float4*>(Wg + i * 96 + kc * 32 + k4);
      Wc[i * WLD + k4 + 0] = v.x;
      Wc[i * WLD + k4 + 1] = v.y;
      Wc[i * WLD + k4 + 2] = v.z;
      Wc[i * WLD + k4 + 3] = v.w;
    }
#pragma unroll
    for (int it = 0; it < 12; ++it) {
      int c = lane + it * 64;
      int kk = c / 24;
      int j4 = (c % 24) << 2;
      const float4 v =
          *reinterpret_cast<const float4*>(Sg + (kc * 32 + kk) * 96 + j4);
      *reinterpret_cast<float4*>(&Sc[kk * 100 + j4]) = v;
    }
    WFENCE();
#pragma unroll 2
    for (int kk = 0; kk < 32; ++kk) {
      float wv[12];
#pragma unroll
      for (int r = 0; r < 12; ++r) wv[r] = Wc[(i0 + r) * WLD + kk];
      float sv[12];
      const float4 s0 = *reinterpret_cast<const float4*>(&Sc[kk * 100 + j0]);
      const float4 s1 =
          *reinterpret_cast<const float4*>(&Sc[kk * 100 + j0 + 4]);
      const float4 s2 =
          *reinterpret_cast<const float4*>(&Sc[kk * 100 + j0 + 8]);
      sv[0] = s0.x; sv[1] = s0.y; sv[2] = s0.z; sv[3] = s0.w;
      sv[4] = s1.x; sv[5] = s1.y; sv[6] = s1.z; sv[7] = s1.w;
      sv[8] = s2.x; sv[9] = s2.y; sv[10] = s2.z; sv[11] = s2.w;
#pragma unroll
      for (int a = 0; a < 12; ++a)
#pragma unroll
        for (int b = 0; b < 12; ++b) acc[a][b] += wv[a] * sv[b];
    }
    WFENCE();
  }

  // Al = acc + I
#pragma unroll
  for (int a = 0; a < 12; ++a) {
    int i = i0 + a;
#pragma unroll
    for (int c4 = 0; c4 < 3; ++c4) {
      float4 v;
      v.x = acc[a][c4 * 4 + 0] + ((i == j0 + c4 * 4 + 0) ? 1.f : 0.f);
      v.y = acc[a][c4 * 4 + 1] + ((i == j0 + c4 * 4 + 1) ? 1.f : 0.f);
      v.z = acc[a][c4 * 4 + 2] + ((i == j0 + c4 * 4 + 2) ? 1.f : 0.f);
      v.w = acc[a][c4 * 4 + 3] + ((i == j0 + c4 * 4 + 3) ? 1.f : 0.f);
      *reinterpret_cast<float4*>(&Al[i * ALD + j0 + c4 * 4]) = v;
    }
  }
  WFENCE();

  // ======================= blocked LU, NB = 8 ==============================
  float ls = 0.f;
  int neg = 0;
  int sgn = 0;

  for (int p = 0; p < 12; ++p) {
    const int c0 = p * 8;
    const int NC = 88 - c0;
    const int NT = NC >> 2;
    const bool e0 = lane <= 95 - c0;
    const bool e1 = (c0 < 32) && (lane <= 31 - c0);

    float P0[8], P1[8];
#pragma unroll
    for (int m = 0; m < 8; ++m) { P0[m] = 0.f; P1[m] = 0.f; }
    if (e0) {
      const float4 x =
          *reinterpret_cast<const float4*>(&Al[(c0 + lane) * ALD + c0]);
      const float4 y =
          *reinterpret_cast<const float4*>(&Al[(c0 + lane) * ALD + c0 + 4]);
      P0[0] = x.x; P0[1] = x.y; P0[2] = x.z; P0[3] = x.w;
      P0[4] = y.x; P0[5] = y.y; P0[6] = y.z; P0[7] = y.w;
    }
    if (e1) {
      const float4 x =
          *reinterpret_cast<const float4*>(&Al[(c0 + 64 + lane) * ALD + c0]);
      const float4 y =
          *reinterpret_cast<const float4*>(&Al[(c0 + 64 + lane) * ALD + c0 + 4]);
      P1[0] = x.x; P1[1] = x.y; P1[2] = x.z; P1[3] = x.w;
      P1[4] = y.x; P1[5] = y.y; P1[6] = y.z; P1[7] = y.w;
    }

#pragma unroll
    for (int j = 0; j < 8; ++j) {
      const int jc = c0 + j;
      float pv;
      int tried = 0;
      for (;;) {
        pv = __shfl(P0[j], j);
        if (fabsf(pv) >= 1e-3f || tried) break;
        tried = 1;
        unsigned k0 = (e0 && lane >= j)
                          ? ((__float_as_uint(fabsf(P0[j])) & ~127u) |
                             (unsigned)lane)
                          : 0u;
        unsigned k1 = e1 ? ((__float_as_uint(fabsf(P1[j])) & ~127u) | 64u |
                            (unsigned)lane)
                         : 0u;
        unsigned key = k0 > k1 ? k0 : k1;
#pragma unroll
        for (int m = 1; m < 64; m <<= 1) {
          unsigned o = (unsigned)__shfl_xor((int)key, m);
          key = key > o ? key : o;
        }
        const int wl = (int)(key & 63u);
        const int slot = (int)((key >> 6) & 1u);
        const int bi = c0 + slot * 64 + wl;
        if (bi <= jc) break;
        sgn ^= 1;
#pragma unroll
        for (int m = 0; m < 8; ++m) {
          const float vj = __shfl(P0[m], j);
          const float vb0 = __shfl(P0[m], wl);
          const float vb1 = __shfl(P1[m], wl);
          const float vb = slot ? vb1 : vb0;
          if (lane == j) P0[m] = vb;
          if (lane == wl) {
            if (slot) P1[m] = vj;
            else P0[m] = vj;
          }
        }
        if (lane < NT) {
          const int col0 = c0 + 8 + lane * 4;
          float4 xx = *reinterpret_cast<float4*>(&Al[jc * ALD + col0]);
          float4 yy = *reinterpret_cast<float4*>(&Al[bi * ALD + col0]);
          *reinterpret_cast<float4*>(&Al[jc * ALD + col0]) = yy;
          *reinterpret_cast<float4*>(&Al[bi * ALD + col0]) = xx;
        }
        WFENCE();
      }
      const float rpv = __builtin_amdgcn_rcpf(pv);
      const bool up0 = e0 && (lane > j);
      const float L0 = P0[j] * rpv;
      const float L1 = P1[j] * rpv;
      if (up0) P0[j] = L0;
      if (e1) P1[j] = L1;
#pragma unroll
      for (int jj = j + 1; jj < 8; ++jj) {
        const float u = __shfl(P0[jj], j);
        if (up0) P0[jj] -= L0 * u;
        if (e1) P1[jj] -= L1 * u;
      }
      ls += logf(fabsf(pv));
      if (pv < 0.f) neg ^= 1;
    }
    WFENCE();

    if (NC > 0) {
      // U12 solve
      const int ca = c0 + 8 + lane;
      const bool va = lane < NC;
      const int cb = ca + 64;
      const bool vb = (lane + 64) < NC;
      float a[8], b[8];
#pragma unroll
      for (int i = 0; i < 8; ++i) {
        a[i] = va ? Al[(c0 + i) * ALD + ca] : 0.f;
        b[i] = vb ? Al[(c0 + i) * ALD + cb] : 0.f;
      }
#pragma unroll
      for (int jj = 1; jj < 8; ++jj)
#pragma unroll
        for (int i = 0; i < jj; ++i) {
          const float Lv = __shfl(P0[i], jj);
          a[jj] -= Lv * a[i];
          b[jj] -= Lv * b[i];
        }
#pragma unroll
      for (int i = 0; i < 8; ++i) {
        if (va) Al[(c0 + i) * ALD + ca] = a[i];
        if (vb) Al[(c0 + i) * ALD + cb] = b[i];
      }
      WFENCE();

      // trailing rank-8 update
      const bool r0v = e0 && (lane >= 8);
      const bool r1v = e1;
      const int r0 = (c0 + lane) * ALD;
      const int r1 = (c0 + 64 + lane) * ALD;
      for (int ct = 0; ct < NT; ++ct) {
        const int col0 = c0 + 8 + ct * 4;
        float4 u[8];
#pragma unroll
        for (int i = 0; i < 8; ++i)
          u[i] = *reinterpret_cast<const float4*>(&Al[(c0 + i) * ALD + col0]);
        if (r0v) {
          float4 x = *reinterpret_cast<float4*>(&Al[r0 + col0]);
#pragma unroll
          for (int i = 0; i < 8; ++i) {
            x.x -= P0[i] * u[i].x;
            x.y -= P0[i] * u[i].y;
            x.z -= P0[i] * u[i].z;
            x.w -= P0[i] * u[i].w;
          }
          *reinterpret_cast<float4*>(&Al[r0 + col0]) = x;
        }
        if (r1v) {
          float4 x = *reinterpret_cast<float4*>(&Al[r1 + col0]);
#pragma unroll
          for (int i = 0; i < 8; ++i) {
            x.x -= P1[i] * u[i].x;
            x.y -= P1[i] * u[i].y;
            x.z -= P1[i] * u[i].z;
            x.w -= P1[i] * u[i].w;
          }
          *reinterpret_cast<float4*>(&Al[r1 + col0]) = x;
        }
      }
    }
    WFENCE();
  }

  if (lane == 0) {
    const float LMIN = -11.5129254f, LMAX = 11.5129254f;  // log(1e-5), log(1e5)
    float c;
    if (neg ^ sgn) c = LMIN;
    else c = fminf(fmaxf(ls, LMIN), LMAX);
    logdet[f] = c;
  }
}

// ---------------------------------------------------------------------------
// quad body (identical math to R6's quad_kernel; smem reinterpreted).
// ---------------------------------------------------------------------------
__device__ __forceinline__ void quad_body(const int tid, const int idx,
                                          const float* __restrict__ z,
                                          const float* __restrict__ W,
                                          float* __restrict__ partial,
                                          float* smem) {
  unsigned short* Zb = reinterpret_cast<unsigned short*>(smem);
  unsigned short* Wb = Zb + 128 * ZLD;   // 13,312 shorts in

  const int lane = tid & 63, wave = tid >> 6;
  const int n0 = (idx & 31) * 128;
  const int f0 = (idx >> 5) * 16;
  const int lrow = lane & 15;
  const int lq = lane >> 4;
  const int lk8 = lq * 8;
  const int rgrp = tid >> 3;
  const int cgrp = tid & 7;

  float dotacc[2][4];
#pragma unroll
  for (int mt = 0; mt < 2; ++mt)
#pragma unroll
    for (int i = 0; i < 4; ++i) dotacc[mt][i] = 0.f;

  for (int ff = 0; ff < 16; ++ff) {
    const int f = f0 + ff;
#pragma unroll
    for (int p = 0; p < 4; ++p) {
      int r = p * 32 + rgrp;
      const float4* src = reinterpret_cast<const float4*>(
          z + (size_t)(n0 + r) * 24576 + (size_t)f * 96);
#pragma unroll
      for (int cc = 0; cc < 3; ++cc) {
        int c = cgrp + cc * 8;
        float4 d = src[c];
        ushort4 s;
        s.x = f2bf(d.x); s.y = f2bf(d.y); s.z = f2bf(d.z); s.w = f2bf(d.w);
        *reinterpret_cast<ushort4*>(&Zb[r * ZLD + c * 4]) = s;
      }
    }
    const float4* wsrc =
        reinterpret_cast<const float4*>(W + (size_t)f * 9216);
#pragma unroll
    for (int it = 0; it < 9; ++it) {
      int c = tid + it * 256;
      int k = c / 24, q4 = (c % 24) << 2;
      float4 d = wsrc[c];
      ushort4 s;
      s.x = f2bf(d.x); s.y = f2bf(d.y); s.z = f2bf(d.z); s.w = f2bf(d.w);
      *reinterpret_cast<ushort4*>(&Wb[k * ZLD + q4]) = s;
    }
    __syncthreads();

    f32x4 acc[2][6];
#pragma unroll
    for (int mt = 0; mt < 2; ++mt)
#pragma unroll
      for (int nt = 0; nt < 6; ++nt) acc[mt][nt] = (f32x4){0.f, 0.f, 0.f, 0.f};

#pragma unroll
    for (int ks = 0; ks < 3; ++ks) {
      bf16x8 a0 = *reinterpret_cast<const bf16x8*>(
          &Zb[(wave * 32 + lrow) * ZLD + ks * 32 + lk8]);
      bf16x8 a1 = *reinterpret_cast<const bf16x8*>(
          &Zb[(wave * 32 + 16 + lrow) * ZLD + ks * 32 + lk8]);
#pragma unroll
      for (int nt = 0; nt < 6; ++nt) {
        bf16x8 b = *reinterpret_cast<const bf16x8*>(
            &Wb[(nt * 16 + lrow) * ZLD + ks * 32 + lk8]);
        acc[0][nt] =
            __builtin_amdgcn_mfma_f32_16x16x32_bf16(a0, b, acc[0][nt], 0, 0, 0);
        acc[1][nt] =
            __builtin_amdgcn_mfma_f32_16x16x32_bf16(a1, b, acc[1][nt], 0, 0, 0);
      }
    }

#pragma unroll
    for (int mt = 0; mt < 2; ++mt) {
      int rbase = wave * 32 + mt * 16 + lq * 4;
#pragma unroll
      for (int i = 0; i < 4; ++i) {
        int row = rbase + i;
        float s = 0.f;
#pragma unroll
        for (int nt = 0; nt < 6; ++nt) {
          float zv = bf2f(Zb[row * ZLD + nt * 16 + lrow]);
          s += acc[mt][nt][i] * zv;
        }
        dotacc[mt][i] += s;
      }
    }
    __syncthreads();
  }

#pragma unroll
  for (int mt = 0; mt < 2; ++mt)
#pragma unroll
    for (int i = 0; i < 4; ++i) {
      float v = dotacc[mt][i];
      v += __shfl_xor(v, 1);
      v += __shfl_xor(v, 2);
      v += __shfl_xor(v, 4);
      v += __shfl_xor(v, 8);
      dotacc[mt][i] = v;
    }
  if (lrow == 0) {
#pragma unroll
    for (int mt = 0; mt < 2; ++mt) {
      int row = wave * 32 + mt * 16 + lq * 4;
      float4 o = {dotacc[mt][0], dotacc[mt][1], dotacc[mt][2], dotacc[mt][3]};
      *reinterpret_cast<float4*>(
          &partial[(size_t)(idx >> 5) * 4096 + n0 + row]) = o;
    }
  }
}

// ---------------------------------------------------------------------------
// Fused kernel: blocks 0..255 det (dispatch first -> 1/CU), 256..767 quad.
// ---------------------------------------------------------------------------
__global__ __launch_bounds__(256) void fused_kernel(
    const float* __restrict__ z, const float* __restrict__ W,
    const float* __restrict__ S1, float* __restrict__ partial,
    float* __restrict__ logdet) {
  __shared__ alignas(16) float smem[16160];   // 64,640 B union
  if (blockIdx.x < 256) {
    if (threadIdx.x >= 64) return;            // det is single-wave
    det_body(threadIdx.x, blockIdx.x, W, S1, logdet, smem);
  } else {
    quad_body(threadIdx.x, blockIdx.x - 256, z, W, partial, smem);
  }
}

// ---------------------------------------------------------------------------
// finalize: out[n] = sum_ft partial[ft][n] - sum_f logdet[f] + log(n1/n2)
// ---------------------------------------------------------------------------
__global__ __launch_bounds__(256) void finalize_kernel(
    const float* __restrict__ partial, const float* __restrict__ logdet,
    const int* __restrict__ n1p, const int* __restrict__ n2p,
    float* __restrict__ out) {
  __shared__ float red[256];
  const int t = threadIdx.x;
  red[t] = logdet[t];
  __syncthreads();
  for (int s = 128; s > 0; s >>= 1) {
    if (t < s) red[t] += red[t + s];
    __syncthreads();
  }
  const float S = red[0];
  const int n = blockIdx.x * 256 + t;
  float acc = 0.f;
#pragma unroll
  for (int ft = 0; ft < 16; ++ft) acc += partial[ft * 4096 + n];
  const float cst = logf((float)(*n1p) / (float)(*n2p));
  out[n] = acc - S + cst;
}

// ---------------------------------------------------------------------------
extern "C" void kernel_launch(void* const* d_in, const int* in_sizes, int n_in,
                              void* d_out, int out_size, void* d_ws,
                              size_t ws_size, hipStream_t stream) {
  const float* z  = (const float*)d_in[0];
  const float* s1 = (const float*)d_in[1];
  // d_in[2] = sigma_2 (unused by the reference)
  const float* w  = (const float*)d_in[3];
  const int* n1   = (const int*)d_in[4];
  const int* n2   = (const int*)d_in[5];
  float* out      = (float*)d_out;

  char* ws = (char*)d_ws;
  float* partial = (float*)ws;                 // 16*4096*4 = 262,144 B
  float* logdet  = (float*)(ws + 262144);      // 256*4     =   1,024 B

  fused_kernel<<<dim3(768), dim3(256), 0, stream>>>(z, w, s1, partial, logdet);
  finalize_kernel<<<dim3(16), dim3(256), 0, stream>>>(partial, logdet, n1, n2,
                                                      out);
}

// Round 5
// 651.261 us; speedup vs baseline: 1.3428x; 1.0152x over previous
//
#include <hip/hip_runtime.h>

// ---------------------------------------------------------------------------
// out[n] = sum_f ( z_nf^T W_f z_nf - log(clip(det(W_f S1_f + I),1e-5,1e5)) )
//          + log(n1/n2)
// N=4096, K=256, P2=96
//
// R8: LDS overlay in det -> 3 blocks/CU, full grid residency:
//  - det's Wc (13,440 B) + Sc (12,800 B) are only read during the GEMM
//    phase, strictly before Al (38,400 B) is first written (acc lives in
//    registers). Single-wave DS pipe is in-order -> overlay Wc/Sc inside
//    Al's footprint. det LDS: 64,640 -> 38,400 B.
//  - fused block LDS = union = quad's 46,592 B -> 3 blocks/CU; grid 768 =
//    3 x 256 CUs -> ALL blocks resident at t=0. Each CU: ~1 det block
//    (1 wave, latency-bound, hides under memory waits) + ~2 quad blocks
//    (same quad density as the standalone 110 us run).
//  - all math byte-identical to R7.
// finalize unchanged.
// ---------------------------------------------------------------------------

typedef __attribute__((ext_vector_type(8))) short bf16x8;
typedef __attribute__((ext_vector_type(4))) float f32x4;

#define WFENCE() asm volatile("" ::: "memory")

__device__ __forceinline__ unsigned short f2bf(float x) {
  unsigned int u = __builtin_bit_cast(unsigned int, x);
  u += 0x7fffu + ((u >> 16) & 1u);   // round-to-nearest-even
  return (unsigned short)(u >> 16);
}
__device__ __forceinline__ float bf2f(unsigned short h) {
  unsigned int u = ((unsigned int)h) << 16;
  return __builtin_bit_cast(float, u);
}

#define ALD 100   // Al row stride (dwords)
#define WLD 35    // Wc row stride
#define ZLD 104

// ---------------------------------------------------------------------------
// det body: one wave, barrier-free (single-wave LDS is in-order).
// smem overlay: Wc[0..3360) Sc[3360..6560) during GEMM; Al[0..9600) after.
// ---------------------------------------------------------------------------
__device__ __forceinline__ void det_body(const int lane, const int f,
                                         const float* __restrict__ W,
                                         const float* __restrict__ S1,
                                         float* __restrict__ logdet,
                                         float* smem) {
  float* Wc = smem;          // 96*35 = 3,360 floats (GEMM phase only)
  float* Sc = smem + 3360;   // 32*100 = 3,200 floats (GEMM phase only)
  float* Al = smem;          // 96*100 = 9,600 floats (written after GEMM)

  const float* Wg = W + (size_t)f * 9216;
  const float* Sg = S1 + (size_t)f * 9216;

  const int i0 = (lane >> 3) * 12;
  const int j0 = (lane & 7) * 12;

  float acc[12][12];
#pragma unroll
  for (int a = 0; a < 12; ++a)
#pragma unroll
    for (int b = 0; b < 12; ++b) acc[a][b] = 0.f;

  for (int kc = 0; kc < 3; ++kc) {
#pragma unroll
    for (int it = 0; it < 12; ++it) {
      int c = lane + it * 64;          // 0..767
      int i = c >> 3;
      int k4 = (c & 7) << 2;
      const float4 v =
          *reinterpret_cast<const float4*>(Wg + i * 96 + kc * 32 + k4);
      Wc[i * WLD + k4 + 0] = v.x;
      Wc[i * WLD + k4 + 1] = v.y;
      Wc[i * WLD + k4 + 2] = v.z;
      Wc[i * WLD + k4 + 3] = v.w;
    }
#pragma unroll
    for (int it = 0; it < 12; ++it) {
      int c = lane + it * 64;
      int kk = c / 24;
      int j4 = (c % 24) << 2;
      const float4 v =
          *reinterpret_cast<const float4*>(Sg + (kc * 32 + kk) * 96 + j4);
      *reinterpret_cast<float4*>(&Sc[kk * 100 + j4]) = v;
    }
    WFENCE();
#pragma unroll 2
    for (int kk = 0; kk < 32; ++kk) {
      float wv[12];
#pragma unroll
      for (int r = 0; r < 12; ++r) wv[r] = Wc[(i0 + r) * WLD + kk];
      float sv[12];
      const float4 s0 = *reinterpret_cast<const float4*>(&Sc[kk * 100 + j0]);
      const float4 s1 =
          *reinterpret_cast<const float4*>(&Sc[kk * 100 + j0 + 4]);
      const float4 s2 =
          *reinterpret_cast<const float4*>(&Sc[kk * 100 + j0 + 8]);
      sv[0] = s0.x; sv[1] = s0.y; sv[2] = s0.z; sv[3] = s0.w;
      sv[4] = s1.x; sv[5] = s1.y; sv[6] = s1.z; sv[7] = s1.w;
      sv[8] = s2.x; sv[9] = s2.y; sv[10] = s2.z; sv[11] = s2.w;
#pragma unroll
      for (int a = 0; a < 12; ++a)
#pragma unroll
        for (int b = 0; b < 12; ++b) acc[a][b] += wv[a] * sv[b];
    }
    WFENCE();
  }

  // Al = acc + I  (overwrites Wc/Sc region -- all GEMM reads already done,
  // single-wave DS pipe is in-order)
#pragma unroll
  for (int a = 0; a < 12; ++a) {
    int i = i0 + a;
#pragma unroll
    for (int c4 = 0; c4 < 3; ++c4) {
      float4 v;
      v.x = acc[a][c4 * 4 + 0] + ((i == j0 + c4 * 4 + 0) ? 1.f : 0.f);
      v.y = acc[a][c4 * 4 + 1] + ((i == j0 + c4 * 4 + 1) ? 1.f : 0.f);
      v.z = acc[a][c4 * 4 + 2] + ((i == j0 + c4 * 4 + 2) ? 1.f : 0.f);
      v.w = acc[a][c4 * 4 + 3] + ((i == j0 + c4 * 4 + 3) ? 1.f : 0.f);
      *reinterpret_cast<float4*>(&Al[i * ALD + j0 + c4 * 4]) = v;
    }
  }
  WFENCE();

  // ======================= blocked LU, NB = 8 ==============================
  float ls = 0.f;
  int neg = 0;
  int sgn = 0;

  for (int p = 0; p < 12; ++p) {
    const int c0 = p * 8;
    const int NC = 88 - c0;
    const int NT = NC >> 2;
    const bool e0 = lane <= 95 - c0;
    const bool e1 = (c0 < 32) && (lane <= 31 - c0);

    float P0[8], P1[8];
#pragma unroll
    for (int m = 0; m < 8; ++m) { P0[m] = 0.f; P1[m] = 0.f; }
    if (e0) {
      const float4 x =
          *reinterpret_cast<const float4*>(&Al[(c0 + lane) * ALD + c0]);
      const float4 y =
          *reinterpret_cast<const float4*>(&Al[(c0 + lane) * ALD + c0 + 4]);
      P0[0] = x.x; P0[1] = x.y; P0[2] = x.z; P0[3] = x.w;
      P0[4] = y.x; P0[5] = y.y; P0[6] = y.z; P0[7] = y.w;
    }
    if (e1) {
      const float4 x =
          *reinterpret_cast<const float4*>(&Al[(c0 + 64 + lane) * ALD + c0]);
      const float4 y =
          *reinterpret_cast<const float4*>(&Al[(c0 + 64 + lane) * ALD + c0 + 4]);
      P1[0] = x.x; P1[1] = x.y; P1[2] = x.z; P1[3] = x.w;
      P1[4] = y.x; P1[5] = y.y; P1[6] = y.z; P1[7] = y.w;
    }

#pragma unroll
    for (int j = 0; j < 8; ++j) {
      const int jc = c0 + j;
      float pv;
      int tried = 0;
      for (;;) {
        pv = __shfl(P0[j], j);
        if (fabsf(pv) >= 1e-3f || tried) break;
        tried = 1;
        unsigned k0 = (e0 && lane >= j)
                          ? ((__float_as_uint(fabsf(P0[j])) & ~127u) |
                             (unsigned)lane)
                          : 0u;
        unsigned k1 = e1 ? ((__float_as_uint(fabsf(P1[j])) & ~127u) | 64u |
                            (unsigned)lane)
                         : 0u;
        unsigned key = k0 > k1 ? k0 : k1;
#pragma unroll
        for (int m = 1; m < 64; m <<= 1) {
          unsigned o = (unsigned)__shfl_xor((int)key, m);
          key = key > o ? key : o;
        }
        const int wl = (int)(key & 63u);
        const int slot = (int)((key >> 6) & 1u);
        const int bi = c0 + slot * 64 + wl;
        if (bi <= jc) break;
        sgn ^= 1;
#pragma unroll
        for (int m = 0; m < 8; ++m) {
          const float vj = __shfl(P0[m], j);
          const float vb0 = __shfl(P0[m], wl);
          const float vb1 = __shfl(P1[m], wl);
          const float vb = slot ? vb1 : vb0;
          if (lane == j) P0[m] = vb;
          if (lane == wl) {
            if (slot) P1[m] = vj;
            else P0[m] = vj;
          }
        }
        if (lane < NT) {
          const int col0 = c0 + 8 + lane * 4;
          float4 xx = *reinterpret_cast<float4*>(&Al[jc * ALD + col0]);
          float4 yy = *reinterpret_cast<float4*>(&Al[bi * ALD + col0]);
          *reinterpret_cast<float4*>(&Al[jc * ALD + col0]) = yy;
          *reinterpret_cast<float4*>(&Al[bi * ALD + col0]) = xx;
        }
        WFENCE();
      }
      const float rpv = __builtin_amdgcn_rcpf(pv);
      const bool up0 = e0 && (lane > j);
      const float L0 = P0[j] * rpv;
      const float L1 = P1[j] * rpv;
      if (up0) P0[j] = L0;
      if (e1) P1[j] = L1;
#pragma unroll
      for (int jj = j + 1; jj < 8; ++jj) {
        const float u = __shfl(P0[jj], j);
        if (up0) P0[jj] -= L0 * u;
        if (e1) P1[jj] -= L1 * u;
      }
      ls += logf(fabsf(pv));
      if (pv < 0.f) neg ^= 1;
    }
    WFENCE();

    if (NC > 0) {
      // U12 solve
      const int ca = c0 + 8 + lane;
      const bool va = lane < NC;
      const int cb = ca + 64;
      const bool vb = (lane + 64) < NC;
      float a[8], b[8];
#pragma unroll
      for (int i = 0; i < 8; ++i) {
        a[i] = va ? Al[(c0 + i) * ALD + ca] : 0.f;
        b[i] = vb ? Al[(c0 + i) * ALD + cb] : 0.f;
      }
#pragma unroll
      for (int jj = 1; jj < 8; ++jj)
#pragma unroll
        for (int i = 0; i < jj; ++i) {
          const float Lv = __shfl(P0[i], jj);
          a[jj] -= Lv * a[i];
          b[jj] -= Lv * b[i];
        }
#pragma unroll
      for (int i = 0; i < 8; ++i) {
        if (va) Al[(c0 + i) * ALD + ca] = a[i];
        if (vb) Al[(c0 + i) * ALD + cb] = b[i];
      }
      WFENCE();

      // trailing rank-8 update
      const bool r0v = e0 && (lane >= 8);
      const bool r1v = e1;
      const int r0 = (c0 + lane) * ALD;
      const int r1 = (c0 + 64 + lane) * ALD;
      for (int ct = 0; ct < NT; ++ct) {
        const int col0 = c0 + 8 + ct * 4;
        float4 u[8];
#pragma unroll
        for (int i = 0; i < 8; ++i)
          u[i] = *reinterpret_cast<const float4*>(&Al[(c0 + i) * ALD + col0]);
        if (r0v) {
          float4 x = *reinterpret_cast<float4*>(&Al[r0 + col0]);
#pragma unroll
          for (int i = 0; i < 8; ++i) {
            x.x -= P0[i] * u[i].x;
            x.y -= P0[i] * u[i].y;
            x.z -= P0[i] * u[i].z;
            x.w -= P0[i] * u[i].w;
          }
          *reinterpret_cast<float4*>(&Al[r0 + col0]) = x;
        }
        if (r1v) {
          float4 x = *reinterpret_cast<float4*>(&Al[r1 + col0]);
#pragma unroll
          for (int i = 0; i < 8; ++i) {
            x.x -= P1[i] * u[i].x;
            x.y -= P1[i] * u[i].y;
            x.z -= P1[i] * u[i].z;
            x.w -= P1[i] * u[i].w;
          }
          *reinterpret_cast<float4*>(&Al[r1 + col0]) = x;
        }
      }
    }
    WFENCE();
  }

  if (lane == 0) {
    const float LMIN = -11.5129254f, LMAX = 11.5129254f;  // log(1e-5), log(1e5)
    float c;
    if (neg ^ sgn) c = LMIN;
    else c = fminf(fmaxf(ls, LMIN), LMAX);
    logdet[f] = c;
  }
}

// ---------------------------------------------------------------------------
// quad body (identical math to R7).
// ---------------------------------------------------------------------------
__device__ __forceinline__ void quad_body(const int tid, const int idx,
                                          const float* __restrict__ z,
                                          const float* __restrict__ W,
                                          float* __restrict__ partial,
                                          float* smem) {
  unsigned short* Zb = reinterpret_cast<unsigned short*>(smem);
  unsigned short* Wb = Zb + 128 * ZLD;   // 13,312 shorts in

  const int lane = tid & 63, wave = tid >> 6;
  const int n0 = (idx & 31) * 128;
  const int f0 = (idx >> 5) * 16;
  const int lrow = lane & 15;
  const int lq = lane >> 4;
  const int lk8 = lq * 8;
  const int rgrp = tid >> 3;
  const int cgrp = tid & 7;

  float dotacc[2][4];
#pragma unroll
  for (int mt = 0; mt < 2; ++mt)
#pragma unroll
    for (int i = 0; i < 4; ++i) dotacc[mt][i] = 0.f;

  for (int ff = 0; ff < 16; ++ff) {
    const int f = f0 + ff;
#pragma unroll
    for (int p = 0; p < 4; ++p) {
      int r = p * 32 + rgrp;
      const float4* src = reinterpret_cast<const float4*>(
          z + (size_t)(n0 + r) * 24576 + (size_t)f * 96);
#pragma unroll
      for (int cc = 0; cc < 3; ++cc) {
        int c = cgrp + cc * 8;
        float4 d = src[c];
        ushort4 s;
        s.x = f2bf(d.x); s.y = f2bf(d.y); s.z = f2bf(d.z); s.w = f2bf(d.w);
        *reinterpret_cast<ushort4*>(&Zb[r * ZLD + c * 4]) = s;
      }
    }
    const float4* wsrc =
        reinterpret_cast<const float4*>(W + (size_t)f * 9216);
#pragma unroll
    for (int it = 0; it < 9; ++it) {
      int c = tid + it * 256;
      int k = c / 24, q4 = (c % 24) << 2;
      float4 d = wsrc[c];
      ushort4 s;
      s.x = f2bf(d.x); s.y = f2bf(d.y); s.z = f2bf(d.z); s.w = f2bf(d.w);
      *reinterpret_cast<ushort4*>(&Wb[k * ZLD + q4]) = s;
    }
    __syncthreads();

    f32x4 acc[2][6];
#pragma unroll
    for (int mt = 0; mt < 2; ++mt)
#pragma unroll
      for (int nt = 0; nt < 6; ++nt) acc[mt][nt] = (f32x4){0.f, 0.f, 0.f, 0.f};

#pragma unroll
    for (int ks = 0; ks < 3; ++ks) {
      bf16x8 a0 = *reinterpret_cast<const bf16x8*>(
          &Zb[(wave * 32 + lrow) * ZLD + ks * 32 + lk8]);
      bf16x8 a1 = *reinterpret_cast<const bf16x8*>(
          &Zb[(wave * 32 + 16 + lrow) * ZLD + ks * 32 + lk8]);
#pragma unroll
      for (int nt = 0; nt < 6; ++nt) {
        bf16x8 b = *reinterpret_cast<const bf16x8*>(
            &Wb[(nt * 16 + lrow) * ZLD + ks * 32 + lk8]);
        acc[0][nt] =
            __builtin_amdgcn_mfma_f32_16x16x32_bf16(a0, b, acc[0][nt], 0, 0, 0);
        acc[1][nt] =
            __builtin_amdgcn_mfma_f32_16x16x32_bf16(a1, b, acc[1][nt], 0, 0, 0);
      }
    }

#pragma unroll
    for (int mt = 0; mt < 2; ++mt) {
      int rbase = wave * 32 + mt * 16 + lq * 4;
#pragma unroll
      for (int i = 0; i < 4; ++i) {
        int row = rbase + i;
        float s = 0.f;
#pragma unroll
        for (int nt = 0; nt < 6; ++nt) {
          float zv = bf2f(Zb[row * ZLD + nt * 16 + lrow]);
          s += acc[mt][nt][i] * zv;
        }
        dotacc[mt][i] += s;
      }
    }
    __syncthreads();
  }

#pragma unroll
  for (int mt = 0; mt < 2; ++mt)
#pragma unroll
    for (int i = 0; i < 4; ++i) {
      float v = dotacc[mt][i];
      v += __shfl_xor(v, 1);
      v += __shfl_xor(v, 2);
      v += __shfl_xor(v, 4);
      v += __shfl_xor(v, 8);
      dotacc[mt][i] = v;
    }
  if (lrow == 0) {
#pragma unroll
    for (int mt = 0; mt < 2; ++mt) {
      int row = wave * 32 + mt * 16 + lq * 4;
      float4 o = {dotacc[mt][0], dotacc[mt][1], dotacc[mt][2], dotacc[mt][3]};
      *reinterpret_cast<float4*>(
          &partial[(size_t)(idx >> 5) * 4096 + n0 + row]) = o;
    }
  }
}

// ---------------------------------------------------------------------------
// Fused kernel: blocks 0..255 det, 256..767 quad. LDS = 46,592 B union ->
// 3 blocks/CU, 768 blocks = full residency on 256 CUs.
// ---------------------------------------------------------------------------
__global__ __launch_bounds__(256) void fused_kernel(
    const float* __restrict__ z, const float* __restrict__ W,
    const float* __restrict__ S1, float* __restrict__ partial,
    float* __restrict__ logdet) {
  __shared__ alignas(16) float smem[11648];   // 46,592 B union
  if (blockIdx.x < 256) {
    if (threadIdx.x >= 64) return;            // det is single-wave
    det_body(threadIdx.x, blockIdx.x, W, S1, logdet, smem);
  } else {
    quad_body(threadIdx.x, blockIdx.x - 256, z, W, partial, smem);
  }
}

// ---------------------------------------------------------------------------
// finalize: out[n] = sum_ft partial[ft][n] - sum_f logdet[f] + log(n1/n2)
// ---------------------------------------------------------------------------
__global__ __launch_bounds__(256) void finalize_kernel(
    const float* __restrict__ partial, const float* __restrict__ logdet,
    const int* __restrict__ n1p, const int* __restrict__ n2p,
    float* __restrict__ out) {
  __shared__ float red[256];
  const int t = threadIdx.x;
  red[t] = logdet[t];
  __syncthreads();
  for (int s = 128; s > 0; s >>= 1) {
    if (t < s) red[t] += red[t + s];
    __syncthreads();
  }
  const float S = red[0];
  const int n = blockIdx.x * 256 + t;
  float acc = 0.f;
#pragma unroll
  for (int ft = 0; ft < 16; ++ft) acc += partial[ft * 4096 + n];
  const float cst = logf((float)(*n1p) / (float)(*n2p));
  out[n] = acc - S + cst;
}

// ---------------------------------------------------------------------------
extern "C" void kernel_launch(void* const* d_in, const int* in_sizes, int n_in,
                              void* d_out, int out_size, void* d_ws,
                              size_t ws_size, hipStream_t stream) {
  const float* z  = (const float*)d_in[0];
  const float* s1 = (const float*)d_in[1];
  // d_in[2] = sigma_2 (unused by the reference)
  const float* w  = (const float*)d_in[3];
  const int* n1   = (const int*)d_in[4];
  const int* n2   = (const int*)d_in[5];
  float* out      = (float*)d_out;

  char* ws = (char*)d_ws;
  float* partial = (float*)ws;                 // 16*4096*4 = 262,144 B
  float* logdet  = (float*)(ws + 262144);      // 256*4     =   1,024 B

  fused_kernel<<<dim3(768), dim3(256), 0, stream>>>(z, w, s1, partial, logdet);
  finalize_kernel<<<dim3(16), dim3(256), 0, stream>>>(partial, logdet, n1, n2,
                                                      out);
}